// Round 3
// baseline (891.914 us; speedup 1.0000x reference)
//
#include <hip/hip_runtime.h>

#define Bn 4
#define Cn 256
#define CQn 64
#define Nn 4096

using f32x4  = __attribute__((ext_vector_type(4))) float;
using half4  = __attribute__((ext_vector_type(4))) _Float16;
using half8  = __attribute__((ext_vector_type(8))) _Float16;

#define MFMA_F16(a, b, c)  __builtin_amdgcn_mfma_f32_16x16x32_f16((a), (b), (c), 0, 0, 0)
// XOR swizzle on byte-in-row: flips bits 4..6 by (row&7). Same involution on both
// write and read sides. Makes 16-lane row-strided ds_read_b128 2-way (free).
#define SWZ(row, byte) ((unsigned)(byte) ^ ((((unsigned)(row)) & 7u) << 4))

// LDS tiles with 128-byte rows (64 f16), swizzled.
__device__ __forceinline__ half8 lds_read8(const _Float16* base, int row, int slot) {
  return *(const half8*)((const char*)base + row * 128 + SWZ(row, slot * 16));
}

// ---------------------------------------------------------------------------
// proj_all: all 5 projections. z = 0:q<-x3, 1:k1<-x1, 2:k2<-x2, 3:v<-x3, 4:vt<-xt.
// (unchanged from round 2 — measured fine)
// ---------------------------------------------------------------------------
__global__ __launch_bounds__(256) void proj_all(
    const float* __restrict__ x1, const float* __restrict__ x2,
    const float* __restrict__ x3, const float* __restrict__ xt,
    const float* __restrict__ Wq, const float* __restrict__ bq,
    const float* __restrict__ Wk, const float* __restrict__ bk,
    const float* __restrict__ Wk2, const float* __restrict__ bk2,
    const float* __restrict__ Wv, const float* __restrict__ bv,
    const float* __restrict__ Wv2, const float* __restrict__ bv2,
    _Float16* __restrict__ qt, _Float16* __restrict__ k1t, _Float16* __restrict__ k2t,
    _Float16* __restrict__ v, _Float16* __restrict__ vt)
{
  const int p = blockIdx.z;
  const float* x    = (p == 0 || p == 3) ? x3 : (p == 1) ? x1 : (p == 2) ? x2 : xt;
  const float* W    = (p == 0) ? Wq : (p == 1) ? Wk : (p == 2) ? Wk2 : (p == 3) ? Wv : Wv2;
  const float* bias = (p == 0) ? bq : (p == 1) ? bk : (p == 2) ? bk2 : (p == 3) ? bv : bv2;

  const int b = blockIdx.y;
  const int n0 = blockIdx.x * 64;
  const int tid = threadIdx.x;
  const int w = tid >> 6, lane = tid & 63, quad = lane >> 4, l16 = lane & 15;

  __shared__ _Float16 xT[64 * 256];   // [n][c], 512 B rows, swizzled. 32 KB.

  {
    const int nq = (tid & 15) * 4;
#pragma unroll
    for (int it = 0; it < 4; ++it) {
      const int cg = it * 64 + (tid >> 4) * 4;
      f32x4 xv[4];
#pragma unroll
      for (int ci = 0; ci < 4; ++ci)
        xv[ci] = *(const f32x4*)(x + ((size_t)b * Cn + cg + ci) * Nn + n0 + nq);
#pragma unroll
      for (int ni = 0; ni < 4; ++ni) {
        const int row = nq + ni;
        half4 hv;
#pragma unroll
        for (int ci = 0; ci < 4; ++ci) hv[ci] = (_Float16)xv[ci][ni];
        *(half4*)((char*)xT + row * 512 + SWZ(row, cg * 2)) = hv;
      }
    }
  }
  __syncthreads();

  if (p < 3) {
    _Float16* out = (p == 0) ? qt : (p == 1) ? k1t : k2t;
    const int row = w * 16 + l16;
    f32x4 acc[4] = {};
    for (int kst = 0; kst < 8; ++kst) {
      const half8 a = *(const half8*)((const char*)xT + row * 512 +
                                      SWZ(row, (kst * 4 + quad) * 16));
#pragma unroll
      for (int s = 0; s < 4; ++s) {
        const int o = s * 16 + l16;
        const f32x4 w0 = *(const f32x4*)(W + (size_t)o * Cn + kst * 32 + quad * 8);
        const f32x4 w1 = *(const f32x4*)(W + (size_t)o * Cn + kst * 32 + quad * 8 + 4);
        half8 bf;
#pragma unroll
        for (int j = 0; j < 4; ++j) { bf[j] = (_Float16)w0[j]; bf[4 + j] = (_Float16)w1[j]; }
        acc[s] = MFMA_F16(a, bf, acc[s]);
      }
    }
#pragma unroll
    for (int s = 0; s < 4; ++s) {
      const int o = s * 16 + l16;
      const float bb = bias[o];
#pragma unroll
      for (int r = 0; r < 4; ++r) {
        const int n = n0 + w * 16 + quad * 4 + r;
        out[((size_t)b * Nn + n) * CQn + o] = (_Float16)(acc[s][r] + bb);
      }
    }
  } else {
    _Float16* out = (p == 3) ? v : vt;
    f32x4 acc[4][4] = {};
    for (int kst = 0; kst < 8; ++kst) {
      half8 bt[4];
#pragma unroll
      for (int tt = 0; tt < 4; ++tt) {
        const int rowx = tt * 16 + l16;
        bt[tt] = *(const half8*)((const char*)xT + rowx * 512 +
                                 SWZ(rowx, (kst * 4 + quad) * 16));
      }
#pragma unroll
      for (int s = 0; s < 4; ++s) {
        const int o = w * 64 + s * 16 + l16;
        const f32x4 w0 = *(const f32x4*)(W + (size_t)o * Cn + kst * 32 + quad * 8);
        const f32x4 w1 = *(const f32x4*)(W + (size_t)o * Cn + kst * 32 + quad * 8 + 4);
        half8 a;
#pragma unroll
        for (int j = 0; j < 4; ++j) { a[j] = (_Float16)w0[j]; a[4 + j] = (_Float16)w1[j]; }
#pragma unroll
        for (int tt = 0; tt < 4; ++tt) acc[s][tt] = MFMA_F16(a, bt[tt], acc[s][tt]);
      }
    }
#pragma unroll
    for (int s = 0; s < 4; ++s) {
#pragma unroll
      for (int r = 0; r < 4; ++r) {
        const int o = w * 64 + s * 16 + quad * 4 + r;
        const float bb = bias[o];
#pragma unroll
        for (int tt = 0; tt < 4; ++tt) {
          const int n = n0 + tt * 16 + l16;
          out[((size_t)b * Cn + o) * Nn + n] = (_Float16)(acc[s][tt][r] + bb);
        }
      }
    }
  }
}

// ---------------------------------------------------------------------------
// attn_flash v2: 256 blocks (1/CU), 1024 threads (16 waves), 64 rows/block.
// K/q/V read DIRECTLY from global (L1/L2-cached, coalesced 16B granules) — no
// LDS staging, since reuse is <=4x (K) or 1x (V). Sweeps 1/2 are barrier-FREE
// register loops the compiler pipelines. Sweep 3 keeps only ppT in LDS,
// TRIPLE-buffered -> ONE barrier per tile:
//   iter t: {V(t) loads issued; S(t+1)->ppT[(t+1)%3]; barrier;
//            PV(t)+attn(t) from ppT[t%3]}.
// Buffer safety: writer (t+1)%3 vs concurrent reader (t-1)%3 always differ.
// LDS ~27 KB. Barriers: ~200 -> ~70.
// ---------------------------------------------------------------------------
__global__ __launch_bounds__(1024, 4) void attn_flash(
    const _Float16* __restrict__ qt, const _Float16* __restrict__ k1t,
    const _Float16* __restrict__ k2t, const _Float16* __restrict__ v,
    const _Float16* __restrict__ vt,
    const float* __restrict__ x3, const float* __restrict__ xt,
    const float* __restrict__ gamma, const float* __restrict__ gamma2,
    float* __restrict__ attn, float* __restrict__ out1, float* __restrict__ out2)
{
  __shared__ _Float16 ppT[3][64 * 64];      // 24 KB, swizzled 128B rows
  __shared__ float red[16][2][16];
  __shared__ float rLs[64];

  const int i = blockIdx.x;
  const int b = (i & 7) >> 1;                   // batch pinned to XCD pair
  const int nt = ((i >> 3) << 1) | (i & 1);     // 0..63
  const int n0 = nt * 64;
  const int tid = threadIdx.x;
  const int w = tid >> 6, lane = tid & 63, quad = lane >> 4, l16 = lane & 15;
  const int ntw = w & 3;     // n-tile (S phases)
  const int ms  = w >> 2;    // m-sub  (S phases)

  const _Float16* k1b = k1t + (size_t)b * Nn * CQn;
  const _Float16* k2b = k2t + (size_t)b * Nn * CQn;
  const _Float16* vb  = v   + (size_t)b * Cn * Nn;
  const _Float16* vtb = vt  + (size_t)b * Cn * Nn;
  const float g1 = gamma[0], g2 = gamma2[0];

  // q fragment straight from global (values identical to old LDS-staged path)
  const _Float16* qrow = qt + ((size_t)b * Nn + n0 + ntw * 16 + l16) * CQn;
  const half8 aq0 = *(const half8*)(qrow + quad * 8);
  const half8 aq1 = *(const half8*)(qrow + 32 + quad * 8);

  // per-thread K row base (row within tile: ms*16+l16; col granule: quad*8)
  const size_t kstep = (size_t)64 * CQn;
  const _Float16* k1r0 = k1b + (size_t)(ms * 16 + l16) * CQn + quad * 8;
  const _Float16* k2r0 = k2b + (size_t)(ms * 16 + l16) * CQn + quad * 8;

  // ================= sweep 1: lg1/lg2 (no barriers) =================
  float l1a[4] = {0.f, 0.f, 0.f, 0.f}, l2a[4] = {0.f, 0.f, 0.f, 0.f};
#pragma unroll 2
  for (int t = 0; t < 64; ++t) {
    const _Float16* k1r = k1r0 + (size_t)t * kstep;
    const _Float16* k2r = k2r0 + (size_t)t * kstep;
    const half8 kb0 = *(const half8*)(k1r);
    const half8 kb1 = *(const half8*)(k1r + 32);
    const half8 kb2 = *(const half8*)(k2r);
    const half8 kb3 = *(const half8*)(k2r + 32);
    f32x4 S1 = {}; S1 = MFMA_F16(aq0, kb0, S1); S1 = MFMA_F16(aq1, kb1, S1);
    f32x4 S2 = {}; S2 = MFMA_F16(aq0, kb2, S2); S2 = MFMA_F16(aq1, kb3, S2);
#pragma unroll
    for (int r = 0; r < 4; ++r) { l1a[r] += __expf(S1[r]); l2a[r] += __expf(S2[r]); }
  }
#pragma unroll
  for (int r = 0; r < 4; ++r)
#pragma unroll
    for (int off = 1; off < 16; off <<= 1) {
      l1a[r] += __shfl_xor(l1a[r], off);
      l2a[r] += __shfl_xor(l2a[r], off);
    }
  if (l16 == 0)
#pragma unroll
    for (int r = 0; r < 4; ++r) { red[w][0][quad * 4 + r] = l1a[r]; red[w][1][quad * 4 + r] = l2a[r]; }
  __syncthreads();
  float lg1[4], lg2[4];
#pragma unroll
  for (int r = 0; r < 4; ++r) {
    const int nn = quad * 4 + r;
    float s1 = 0.f, s2 = 0.f;
#pragma unroll
    for (int msk = 0; msk < 4; ++msk) { s1 += red[ntw + 4 * msk][0][nn]; s2 += red[ntw + 4 * msk][1][nn]; }
    lg1[r] = __logf(s1); lg2[r] = __logf(s2);
  }
  __syncthreads();   // red reused below

  // ================= sweep 2: L -> rLs (no barriers in loop) =================
  float La[4] = {0.f, 0.f, 0.f, 0.f};
#pragma unroll 2
  for (int t = 0; t < 64; ++t) {
    const _Float16* k1r = k1r0 + (size_t)t * kstep;
    const _Float16* k2r = k2r0 + (size_t)t * kstep;
    const half8 kb0 = *(const half8*)(k1r);
    const half8 kb1 = *(const half8*)(k1r + 32);
    const half8 kb2 = *(const half8*)(k2r);
    const half8 kb3 = *(const half8*)(k2r + 32);
    f32x4 S1 = {}; S1 = MFMA_F16(aq0, kb0, S1); S1 = MFMA_F16(aq1, kb1, S1);
    f32x4 S2 = {}; S2 = MFMA_F16(aq0, kb2, S2); S2 = MFMA_F16(aq1, kb3, S2);
#pragma unroll
    for (int r = 0; r < 4; ++r) {
      const float a1 = __expf(S1[r] - lg1[r]);
      const float a2 = __expf(S2[r] - lg2[r]);
      La[r] += __expf(a1 + a2);
    }
  }
#pragma unroll
  for (int r = 0; r < 4; ++r)
#pragma unroll
    for (int off = 1; off < 16; off <<= 1) La[r] += __shfl_xor(La[r], off);
  if (l16 == 0)
#pragma unroll
    for (int r = 0; r < 4; ++r) red[w][0][quad * 4 + r] = La[r];
  __syncthreads();
  if (tid < 64) {
    float s = 0.f;
#pragma unroll
    for (int msk = 0; msk < 4; ++msk) s += red[(tid >> 4) + 4 * msk][0][tid & 15];
    rLs[tid] = 1.0f / s;
  }
  __syncthreads();

  // ================= sweep 3: pp -> ppT (triple buf), PV, attn =================
  // prologue: pp(0) -> ppT[0]
  {
    const half8 kb0 = *(const half8*)(k1r0);
    const half8 kb1 = *(const half8*)(k1r0 + 32);
    const half8 kb2 = *(const half8*)(k2r0);
    const half8 kb3 = *(const half8*)(k2r0 + 32);
    f32x4 S1 = {}; S1 = MFMA_F16(aq0, kb0, S1); S1 = MFMA_F16(aq1, kb1, S1);
    f32x4 S2 = {}; S2 = MFMA_F16(aq0, kb2, S2); S2 = MFMA_F16(aq1, kb3, S2);
#pragma unroll
    for (int r = 0; r < 4; ++r) {
      const float a1 = __expf(S1[r] - lg1[r]);
      const float a2 = __expf(S2[r] - lg2[r]);
      const float ppv = __expf(a1 + a2);
      const int prow = ntw * 16 + quad * 4 + r;
      const int pcol = ms * 16 + l16;
      *(_Float16*)((char*)ppT[0] + prow * 128 + SWZ(prow, pcol * 2)) = (_Float16)ppv;
    }
  }
  __syncthreads();

  // PV addressing: wave w owns c-rows w*16..+16 (read-once -> no LDS for V)
  const _Float16* v1r = vb  + (size_t)(w * 16 + l16) * Nn;
  const _Float16* v2r = vtb + (size_t)(w * 16 + l16) * Nn;
  const int arow = tid >> 4;               // attn-write row 0..63
  const int ac4  = (tid & 15) * 4;         // attn-write col group
  const float arl = rLs[arow];
  float* const abase = attn + ((size_t)b * Nn + n0 + arow) * Nn;

  f32x4 acc[4][2] = {};   // [n-tile][tensor]
#pragma unroll 1
  for (int t = 0; t < 64; ++t) {
    const int m0 = t * 64;
    // issue V loads for THIS tile early (consumed after the barrier)
    half8 va[2], vc[2];
#pragma unroll
    for (int kk = 0; kk < 2; ++kk) {
      va[kk] = *(const half8*)(v1r + m0 + (kk * 4 + quad) * 8);
      vc[kk] = *(const half8*)(v2r + m0 + (kk * 4 + quad) * 8);
    }
    // S(t+1) -> ppT[(t+1)%3]  (phantom at t=63 writes ppT[1], never read)
    {
      const int tn = (t + 1) & 63;
      const _Float16* k1r = k1r0 + (size_t)tn * kstep;
      const _Float16* k2r = k2r0 + (size_t)tn * kstep;
      const half8 kb0 = *(const half8*)(k1r);
      const half8 kb1 = *(const half8*)(k1r + 32);
      const half8 kb2 = *(const half8*)(k2r);
      const half8 kb3 = *(const half8*)(k2r + 32);
      f32x4 S1 = {}; S1 = MFMA_F16(aq0, kb0, S1); S1 = MFMA_F16(aq1, kb1, S1);
      f32x4 S2 = {}; S2 = MFMA_F16(aq0, kb2, S2); S2 = MFMA_F16(aq1, kb3, S2);
      _Float16* pN = ppT[(t + 1) % 3];
#pragma unroll
      for (int r = 0; r < 4; ++r) {
        const float a1 = __expf(S1[r] - lg1[r]);
        const float a2 = __expf(S2[r] - lg2[r]);
        const float ppv = __expf(a1 + a2);
        const int prow = ntw * 16 + quad * 4 + r;
        const int pcol = ms * 16 + l16;
        *(_Float16*)((char*)pN + prow * 128 + SWZ(prow, pcol * 2)) = (_Float16)ppv;
      }
    }
    __syncthreads();                         // ppT[t%3] ready (written iter t-1)
    const _Float16* pT = ppT[t % 3];
    // PV: 16 MFMA
#pragma unroll
    for (int kk = 0; kk < 2; ++kk) {
#pragma unroll
      for (int nn = 0; nn < 4; ++nn) {
        const half8 pb = lds_read8(pT, nn * 16 + l16, kk * 4 + quad);
        acc[nn][0] = MFMA_F16(va[kk], pb, acc[nn][0]);
        acc[nn][1] = MFMA_F16(vc[kk], pb, acc[nn][1]);
      }
    }
    // attn write (fire-and-forget f32x4)
    {
      const half4 h = *(const half4*)((const char*)pT + arow * 128 + SWZ(arow, ac4 * 2));
      f32x4 o;
#pragma unroll
      for (int jj = 0; jj < 4; ++jj) o[jj] = (float)h[jj] * arl;
      *(f32x4*)(abase + m0 + ac4) = o;
    }
  }

  // ---- epilogue: each wave owns distinct c-rows; no cross-wave reduce
#pragma unroll
  for (int nn = 0; nn < 4; ++nn) {
    const float rl = rLs[nn * 16 + l16];
#pragma unroll
    for (int r = 0; r < 4; ++r) {
      const int c = w * 16 + quad * 4 + r;
      const size_t base = ((size_t)b * Cn + c) * Nn + n0 + nn * 16 + l16;
      out1[base] = g1 * acc[nn][0][r] * rl + x3[base];
      out2[base] = g2 * acc[nn][1][r] * rl + xt[base];
    }
  }
}

// ---------------------------------------------------------------------------
extern "C" void kernel_launch(void* const* d_in, const int* in_sizes, int n_in,
                              void* d_out, int out_size, void* d_ws, size_t ws_size,
                              hipStream_t stream) {
  const float* x1  = (const float*)d_in[0];
  const float* x2  = (const float*)d_in[1];
  const float* x3  = (const float*)d_in[2];
  const float* xt  = (const float*)d_in[3];
  const float* Wq  = (const float*)d_in[4];
  const float* bq  = (const float*)d_in[5];
  const float* Wk  = (const float*)d_in[6];
  const float* bk  = (const float*)d_in[7];
  const float* Wk2 = (const float*)d_in[8];
  const float* bk2 = (const float*)d_in[9];
  const float* Wv  = (const float*)d_in[10];
  const float* bv  = (const float*)d_in[11];
  const float* Wv2 = (const float*)d_in[12];
  const float* bv2 = (const float*)d_in[13];
  const float* gamma  = (const float*)d_in[14];
  const float* gamma2 = (const float*)d_in[15];

  float* outp = (float*)d_out;
  float* attn = outp;                                   // B*N*N
  float* out1 = outp + (size_t)Bn * Nn * Nn;            // B*C*N
  float* out2 = out1 + (size_t)Bn * Cn * Nn;

  _Float16* qt  = (_Float16*)d_ws;                      // B*N*CQ f16
  _Float16* k1t = qt + (size_t)Bn * Nn * CQn;
  _Float16* k2t = k1t + (size_t)Bn * Nn * CQn;
  _Float16* v   = k2t + (size_t)Bn * Nn * CQn;          // B*C*N f16
  _Float16* vt  = v + (size_t)Bn * Cn * Nn;

  proj_all<<<dim3(Nn / 64, Bn, 5), 256, 0, stream>>>(
      x1, x2, x3, xt, Wq, bq, Wk, bk, Wk2, bk2, Wv, bv, Wv2, bv2,
      qt, k1t, k2t, v, vt);
  attn_flash<<<dim3(Bn * Nn / 64), 1024, 0, stream>>>(
      qt, k1t, k2t, v, vt, x3, xt, gamma, gamma2, attn, out1, out2);
}

// Round 5
// 770.080 us; speedup vs baseline: 1.1582x; 1.1582x over previous
//
#include <hip/hip_runtime.h>

#define Bn 4
#define Cn 256
#define CQn 64
#define Nn 4096

using f32x4  = __attribute__((ext_vector_type(4))) float;
using half4  = __attribute__((ext_vector_type(4))) _Float16;
using half8  = __attribute__((ext_vector_type(8))) _Float16;

#define MFMA_F16(a, b, c)  __builtin_amdgcn_mfma_f32_16x16x32_f16((a), (b), (c), 0, 0, 0)
// XOR swizzle on byte-in-row: flips bits 4..6 by (row&7). Same involution on both
// write and read sides. Makes 16-lane row-strided ds_read_b128 2-way (free).
#define SWZ(row, byte) ((unsigned)(byte) ^ ((((unsigned)(row)) & 7u) << 4))

// LDS tiles with 128-byte rows (64 f16), swizzled.
__device__ __forceinline__ half8 lds_read8(const _Float16* base, int row, int slot) {
  return *(const half8*)((const char*)base + row * 128 + SWZ(row, slot * 16));
}

// ---------------------------------------------------------------------------
// proj_all: all 5 projections. z = 0:q<-x3, 1:k1<-x1, 2:k2<-x2, 3:v<-x3, 4:vt<-xt.
// (unchanged — measured fine)
// ---------------------------------------------------------------------------
__global__ __launch_bounds__(256) void proj_all(
    const float* __restrict__ x1, const float* __restrict__ x2,
    const float* __restrict__ x3, const float* __restrict__ xt,
    const float* __restrict__ Wq, const float* __restrict__ bq,
    const float* __restrict__ Wk, const float* __restrict__ bk,
    const float* __restrict__ Wk2, const float* __restrict__ bk2,
    const float* __restrict__ Wv, const float* __restrict__ bv,
    const float* __restrict__ Wv2, const float* __restrict__ bv2,
    _Float16* __restrict__ qt, _Float16* __restrict__ k1t, _Float16* __restrict__ k2t,
    _Float16* __restrict__ v, _Float16* __restrict__ vt)
{
  const int p = blockIdx.z;
  const float* x    = (p == 0 || p == 3) ? x3 : (p == 1) ? x1 : (p == 2) ? x2 : xt;
  const float* W    = (p == 0) ? Wq : (p == 1) ? Wk : (p == 2) ? Wk2 : (p == 3) ? Wv : Wv2;
  const float* bias = (p == 0) ? bq : (p == 1) ? bk : (p == 2) ? bk2 : (p == 3) ? bv : bv2;

  const int b = blockIdx.y;
  const int n0 = blockIdx.x * 64;
  const int tid = threadIdx.x;
  const int w = tid >> 6, lane = tid & 63, quad = lane >> 4, l16 = lane & 15;

  __shared__ _Float16 xT[64 * 256];   // [n][c], 512 B rows, swizzled. 32 KB.

  {
    const int nq = (tid & 15) * 4;
#pragma unroll
    for (int it = 0; it < 4; ++it) {
      const int cg = it * 64 + (tid >> 4) * 4;
      f32x4 xv[4];
#pragma unroll
      for (int ci = 0; ci < 4; ++ci)
        xv[ci] = *(const f32x4*)(x + ((size_t)b * Cn + cg + ci) * Nn + n0 + nq);
#pragma unroll
      for (int ni = 0; ni < 4; ++ni) {
        const int row = nq + ni;
        half4 hv;
#pragma unroll
        for (int ci = 0; ci < 4; ++ci) hv[ci] = (_Float16)xv[ci][ni];
        *(half4*)((char*)xT + row * 512 + SWZ(row, cg * 2)) = hv;
      }
    }
  }
  __syncthreads();

  if (p < 3) {
    _Float16* out = (p == 0) ? qt : (p == 1) ? k1t : k2t;
    const int row = w * 16 + l16;
    f32x4 acc[4] = {};
    for (int kst = 0; kst < 8; ++kst) {
      const half8 a = *(const half8*)((const char*)xT + row * 512 +
                                      SWZ(row, (kst * 4 + quad) * 16));
#pragma unroll
      for (int s = 0; s < 4; ++s) {
        const int o = s * 16 + l16;
        const f32x4 w0 = *(const f32x4*)(W + (size_t)o * Cn + kst * 32 + quad * 8);
        const f32x4 w1 = *(const f32x4*)(W + (size_t)o * Cn + kst * 32 + quad * 8 + 4);
        half8 bf;
#pragma unroll
        for (int j = 0; j < 4; ++j) { bf[j] = (_Float16)w0[j]; bf[4 + j] = (_Float16)w1[j]; }
        acc[s] = MFMA_F16(a, bf, acc[s]);
      }
    }
#pragma unroll
    for (int s = 0; s < 4; ++s) {
      const int o = s * 16 + l16;
      const float bb = bias[o];
#pragma unroll
      for (int r = 0; r < 4; ++r) {
        const int n = n0 + w * 16 + quad * 4 + r;
        out[((size_t)b * Nn + n) * CQn + o] = (_Float16)(acc[s][r] + bb);
      }
    }
  } else {
    _Float16* out = (p == 3) ? v : vt;
    f32x4 acc[4][4] = {};
    for (int kst = 0; kst < 8; ++kst) {
      half8 bt[4];
#pragma unroll
      for (int tt = 0; tt < 4; ++tt) {
        const int rowx = tt * 16 + l16;
        bt[tt] = *(const half8*)((const char*)xT + rowx * 512 +
                                 SWZ(rowx, (kst * 4 + quad) * 16));
      }
#pragma unroll
      for (int s = 0; s < 4; ++s) {
        const int o = w * 64 + s * 16 + l16;
        const f32x4 w0 = *(const f32x4*)(W + (size_t)o * Cn + kst * 32 + quad * 8);
        const f32x4 w1 = *(const f32x4*)(W + (size_t)o * Cn + kst * 32 + quad * 8 + 4);
        half8 a;
#pragma unroll
        for (int j = 0; j < 4; ++j) { a[j] = (_Float16)w0[j]; a[4 + j] = (_Float16)w1[j]; }
#pragma unroll
        for (int tt = 0; tt < 4; ++tt) acc[s][tt] = MFMA_F16(a, bt[tt], acc[s][tt]);
      }
    }
#pragma unroll
    for (int s = 0; s < 4; ++s) {
#pragma unroll
      for (int r = 0; r < 4; ++r) {
        const int o = w * 64 + s * 16 + quad * 4 + r;
        const float bb = bias[o];
#pragma unroll
        for (int tt = 0; tt < 4; ++tt) {
          const int n = n0 + tt * 16 + l16;
          out[((size_t)b * Cn + o) * Nn + n] = (_Float16)(acc[s][tt][r] + bb);
        }
      }
    }
  }
}

// ---------------------------------------------------------------------------
// attn_flash v3: 256 blocks (1/CU), 1024 threads (16 waves), 64 rows/block.
// Sweeps 1/2: round-2 staged-K dbuf (proven). Sweep 3 rebuilt to cut LDS BW:
//  - PV operands SWAPPED: A = pp (each wave reads only its 32 n-rows from LDS,
//    64 KB/phase vs 128 KB broadcast), B = V read DIRECT from global (read-once
//    data; per-wave reads only its own 32 c-cols; L2-resident). The 128 KB/phase
//    LDS round-trip for V is gone.
//  - ppT double-buffered, write-BEFORE-barrier / read-AFTER: one barrier/tile.
//  - V(t+1) frags + K(t+2) issued after PV(t); consumed after the next barrier
//    (latency structurally hidden — compiler-proof, unlike round 3).
// LDS ~51 KB. Sweep-3 LDS traffic/phase ~290 KB -> ~100 KB.
// ---------------------------------------------------------------------------
__global__ __launch_bounds__(1024, 4) void attn_flash(
    const _Float16* __restrict__ qt, const _Float16* __restrict__ k1t,
    const _Float16* __restrict__ k2t, const _Float16* __restrict__ v,
    const _Float16* __restrict__ vt,
    const float* __restrict__ x3, const float* __restrict__ xt,
    const float* __restrict__ gamma, const float* __restrict__ gamma2,
    float* __restrict__ attn, float* __restrict__ out1, float* __restrict__ out2)
{
  __shared__ _Float16 Kt[2][2][64 * 64];    // 32 KB [buf][tensor]
  __shared__ _Float16 ppT[2][64 * 64];      // 16 KB, swizzled 128B rows
  __shared__ float red[16][2][16];
  __shared__ float rLs[64];

  const int i = blockIdx.x;
  const int b = (i & 7) >> 1;                   // batch pinned to XCD pair
  const int nt = ((i >> 3) << 1) | (i & 1);     // 0..63
  const int n0 = nt * 64;
  const int tid = threadIdx.x;
  const int w = tid >> 6, lane = tid & 63, quad = lane >> 4, l16 = lane & 15;
  const int ntw = w & 3;     // n-tile (S phases)
  const int ms  = w >> 2;    // m-sub  (S phases)

  const _Float16* k1b = k1t + (size_t)b * Nn * CQn;
  const _Float16* k2b = k2t + (size_t)b * Nn * CQn;
  const _Float16* vb  = v   + (size_t)b * Cn * Nn;
  const _Float16* vtb = vt  + (size_t)b * Cn * Nn;
  const float g1 = gamma[0], g2 = gamma2[0];

  // q fragment straight from global (reused all sweeps)
  const _Float16* qrow = qt + ((size_t)b * Nn + n0 + ntw * 16 + l16) * CQn;
  const half8 aq0 = *(const half8*)(qrow + quad * 8);
  const half8 aq1 = *(const half8*)(qrow + 32 + quad * 8);

  // ---- per-thread K staging geometry (16 KB tile: thread covers 16 B)
  const int k_te  = tid >> 9;
  const int k_row = (tid >> 3) & 63;
  const int k_sl  = tid & 7;
  const size_t kstep = (size_t)64 * CQn;
  const _Float16* kSrcBase = (k_te ? k2b : k1b) + (size_t)k_row * CQn + k_sl * 8;
  _Float16* kDst0 = (_Float16*)((char*)Kt[0][k_te] + k_row * 128 + SWZ(k_row, k_sl * 16));
  _Float16* kDst1 = (_Float16*)((char*)Kt[1][k_te] + k_row * 128 + SWZ(k_row, k_sl * 16));
  // stage K tile 0 into buf 0
  *(half8*)kDst0 = *(const half8*)kSrcBase;
  __syncthreads();

  const int krow = ms * 16 + l16;

  // ================= sweep 1: lg1/lg2 (staged K, 1 barrier/tile) =================
  float l1a[4] = {0.f, 0.f, 0.f, 0.f}, l2a[4] = {0.f, 0.f, 0.f, 0.f};
#pragma unroll 1
  for (int t = 0; t < 64; ++t) {
    const half8 kreg = *(const half8*)(kSrcBase + (size_t)((t + 1) & 63) * kstep);
    const _Float16* Kc0 = Kt[t & 1][0];
    const _Float16* Kc1 = Kt[t & 1][1];
    const half8 kb0 = lds_read8(Kc0, krow, quad);
    const half8 kb1 = lds_read8(Kc0, krow, 4 + quad);
    const half8 kb2 = lds_read8(Kc1, krow, quad);
    const half8 kb3 = lds_read8(Kc1, krow, 4 + quad);
    f32x4 S1 = {}; S1 = MFMA_F16(aq0, kb0, S1); S1 = MFMA_F16(aq1, kb1, S1);
    f32x4 S2 = {}; S2 = MFMA_F16(aq0, kb2, S2); S2 = MFMA_F16(aq1, kb3, S2);
#pragma unroll
    for (int r = 0; r < 4; ++r) { l1a[r] += __expf(S1[r]); l2a[r] += __expf(S2[r]); }
    *(half8*)(((t + 1) & 1) ? kDst1 : kDst0) = kreg;
    __syncthreads();
  }
#pragma unroll
  for (int r = 0; r < 4; ++r)
#pragma unroll
    for (int off = 1; off < 16; off <<= 1) {
      l1a[r] += __shfl_xor(l1a[r], off);
      l2a[r] += __shfl_xor(l2a[r], off);
    }
  if (l16 == 0)
#pragma unroll
    for (int r = 0; r < 4; ++r) { red[w][0][quad * 4 + r] = l1a[r]; red[w][1][quad * 4 + r] = l2a[r]; }
  __syncthreads();
  float lg1[4], lg2[4];
#pragma unroll
  for (int r = 0; r < 4; ++r) {
    const int nn = quad * 4 + r;
    float s1 = 0.f, s2 = 0.f;
#pragma unroll
    for (int msk = 0; msk < 4; ++msk) { s1 += red[ntw + 4 * msk][0][nn]; s2 += red[ntw + 4 * msk][1][nn]; }
    lg1[r] = __logf(s1); lg2[r] = __logf(s2);
  }
  __syncthreads();   // red reused below

  // ================= sweep 2: L -> rLs (staged K; K(0) already in buf0) ========
  float La[4] = {0.f, 0.f, 0.f, 0.f};
#pragma unroll 1
  for (int t = 0; t < 64; ++t) {
    const half8 kreg = *(const half8*)(kSrcBase + (size_t)((t + 1) & 63) * kstep);
    const _Float16* Kc0 = Kt[t & 1][0];
    const _Float16* Kc1 = Kt[t & 1][1];
    const half8 kb0 = lds_read8(Kc0, krow, quad);
    const half8 kb1 = lds_read8(Kc0, krow, 4 + quad);
    const half8 kb2 = lds_read8(Kc1, krow, quad);
    const half8 kb3 = lds_read8(Kc1, krow, 4 + quad);
    f32x4 S1 = {}; S1 = MFMA_F16(aq0, kb0, S1); S1 = MFMA_F16(aq1, kb1, S1);
    f32x4 S2 = {}; S2 = MFMA_F16(aq0, kb2, S2); S2 = MFMA_F16(aq1, kb3, S2);
#pragma unroll
    for (int r = 0; r < 4; ++r) {
      const float a1 = __expf(S1[r] - lg1[r]);
      const float a2 = __expf(S2[r] - lg2[r]);
      La[r] += __expf(a1 + a2);
    }
    *(half8*)(((t + 1) & 1) ? kDst1 : kDst0) = kreg;
    __syncthreads();
  }
  // stage K(1) -> buf1 for sweep 3 (buf0 already holds K(0) via the wrap above;
  // last read of buf1 was before the loop's final barrier -> safe to overwrite)
  *(half8*)kDst1 = *(const half8*)(kSrcBase + kstep);
#pragma unroll
  for (int r = 0; r < 4; ++r)
#pragma unroll
    for (int off = 1; off < 16; off <<= 1) La[r] += __shfl_xor(La[r], off);
  if (l16 == 0)
#pragma unroll
    for (int r = 0; r < 4; ++r) red[w][0][quad * 4 + r] = La[r];
  __syncthreads();
  if (tid < 64) {
    float s = 0.f;
#pragma unroll
    for (int msk = 0; msk < 4; ++msk) s += red[(tid >> 4) + 4 * msk][0][tid & 15];
    rLs[tid] = 1.0f / s;
  }
  __syncthreads();

  // ================= sweep 3: pp (dbuf, 1 barrier/tile) + swapped PV + attn ====
  // prologue: S(0) -> ppT[0]
  {
    const _Float16* Kc0 = Kt[0][0];
    const _Float16* Kc1 = Kt[0][1];
    const half8 kb0 = lds_read8(Kc0, krow, quad);
    const half8 kb1 = lds_read8(Kc0, krow, 4 + quad);
    const half8 kb2 = lds_read8(Kc1, krow, quad);
    const half8 kb3 = lds_read8(Kc1, krow, 4 + quad);
    f32x4 S1 = {}; S1 = MFMA_F16(aq0, kb0, S1); S1 = MFMA_F16(aq1, kb1, S1);
    f32x4 S2 = {}; S2 = MFMA_F16(aq0, kb2, S2); S2 = MFMA_F16(aq1, kb3, S2);
#pragma unroll
    for (int r = 0; r < 4; ++r) {
      const float a1 = __expf(S1[r] - lg1[r]);
      const float a2 = __expf(S2[r] - lg2[r]);
      const float ppv = __expf(a1 + a2);
      const int prow = ntw * 16 + quad * 4 + r;
      const int pcol = ms * 16 + l16;
      *(_Float16*)((char*)ppT[0] + prow * 128 + SWZ(prow, pcol * 2)) = (_Float16)ppv;
    }
  }
  __syncthreads();

  // PV wave grid: ni = w&1 (32 n-rows), ci = w>>1 (32 c-cols)
  const int ni = w & 1, ci = w >> 1;
  const _Float16* vA0 = vb  + (size_t)(ci * 32 +      l16) * Nn + quad * 8;
  const _Float16* vA1 = vb  + (size_t)(ci * 32 + 16 + l16) * Nn + quad * 8;
  const _Float16* vB0 = vtb + (size_t)(ci * 32 +      l16) * Nn + quad * 8;
  const _Float16* vB1 = vtb + (size_t)(ci * 32 + 16 + l16) * Nn + quad * 8;

  const int arow = tid >> 4;               // attn-write row 0..63
  const int ac4  = (tid & 15) * 4;         // attn-write col group
  const float arl = rLs[arow];
  float* const abase = attn + ((size_t)b * Nn + n0 + arow) * Nn;

  // preload V frags for tile 0: vcur[te][cs][kk]
  half8 vcur[2][2][2];
#pragma unroll
  for (int kk = 0; kk < 2; ++kk) {
    vcur[0][0][kk] = *(const half8*)(vA0 + kk * 32);
    vcur[0][1][kk] = *(const half8*)(vA1 + kk * 32);
    vcur[1][0][kk] = *(const half8*)(vB0 + kk * 32);
    vcur[1][1][kk] = *(const half8*)(vB1 + kk * 32);
  }

  f32x4 acc[2][2][2] = {};   // [ns][cs][te]
#pragma unroll 1
  for (int t = 0; t < 64; ++t) {
    const int m0 = t * 64;
    const _Float16* pTc = ppT[t & 1];
    // ---- PV(t): A = pp rows (LDS), B = V cols (regs, loaded last iter)
#pragma unroll
    for (int ns = 0; ns < 2; ++ns) {
      const int prow = ni * 32 + ns * 16 + l16;
#pragma unroll
      for (int kk = 0; kk < 2; ++kk) {
        const half8 ap = lds_read8(pTc, prow, kk * 4 + quad);
#pragma unroll
        for (int cs = 0; cs < 2; ++cs) {
          acc[ns][cs][0] = MFMA_F16(ap, vcur[0][cs][kk], acc[ns][cs][0]);
          acc[ns][cs][1] = MFMA_F16(ap, vcur[1][cs][kk], acc[ns][cs][1]);
        }
      }
    }
    // ---- attn write (tile t, normalized on the fly)
    {
      const half4 h = *(const half4*)((const char*)pTc + arow * 128 + SWZ(arow, ac4 * 2));
      f32x4 o;
#pragma unroll
      for (int jj = 0; jj < 4; ++jj) o[jj] = (float)h[jj] * arl;
      *(f32x4*)(abase + m0 + ac4) = o;
    }
    // ---- issue V(t+1) frags + K(t+2) (consumed after the barrier)
    const int mN = ((t + 1) & 63) * 64;
    half8 vnx[2][2][2];
#pragma unroll
    for (int kk = 0; kk < 2; ++kk) {
      vnx[0][0][kk] = *(const half8*)(vA0 + mN + kk * 32);
      vnx[0][1][kk] = *(const half8*)(vA1 + mN + kk * 32);
      vnx[1][0][kk] = *(const half8*)(vB0 + mN + kk * 32);
      vnx[1][1][kk] = *(const half8*)(vB1 + mN + kk * 32);
    }
    const half8 kreg = *(const half8*)(kSrcBase + (size_t)((t + 2) & 63) * kstep);
    // ---- S(t+1) from Kbuf[(t+1)&1] -> ppT[(t+1)&1]
    {
      const _Float16* Kc0 = Kt[(t + 1) & 1][0];
      const _Float16* Kc1 = Kt[(t + 1) & 1][1];
      const half8 kb0 = lds_read8(Kc0, krow, quad);
      const half8 kb1 = lds_read8(Kc0, krow, 4 + quad);
      const half8 kb2 = lds_read8(Kc1, krow, quad);
      const half8 kb3 = lds_read8(Kc1, krow, 4 + quad);
      f32x4 S1 = {}; S1 = MFMA_F16(aq0, kb0, S1); S1 = MFMA_F16(aq1, kb1, S1);
      f32x4 S2 = {}; S2 = MFMA_F16(aq0, kb2, S2); S2 = MFMA_F16(aq1, kb3, S2);
      _Float16* pN = ppT[(t + 1) & 1];
#pragma unroll
      for (int r = 0; r < 4; ++r) {
        const float a1 = __expf(S1[r] - lg1[r]);
        const float a2 = __expf(S2[r] - lg2[r]);
        const float ppv = __expf(a1 + a2);
        const int prow = ntw * 16 + quad * 4 + r;
        const int pcol = ms * 16 + l16;
        *(_Float16*)((char*)pN + prow * 128 + SWZ(prow, pcol * 2)) = (_Float16)ppv;
      }
    }
    // ---- commit K(t+2) -> Kbuf[t&1] (its last reader finished pre-barrier(t-1))
    *(half8*)((t & 1) ? kDst1 : kDst0) = kreg;
    __syncthreads();
#pragma unroll
    for (int te = 0; te < 2; ++te)
#pragma unroll
      for (int cs = 0; cs < 2; ++cs)
#pragma unroll
        for (int kk = 0; kk < 2; ++kk) vcur[te][cs][kk] = vnx[te][cs][kk];
  }

  // ---- epilogue: wave (ni,ci) owns out[n0+ni*32..+32][ci*32..+32]; 16B stores
#pragma unroll
  for (int ns = 0; ns < 2; ++ns) {
    f32x4 rv;
#pragma unroll
    for (int jj = 0; jj < 4; ++jj) rv[jj] = rLs[ni * 32 + ns * 16 + quad * 4 + jj];
#pragma unroll
    for (int cs = 0; cs < 2; ++cs) {
      const int c = ci * 32 + cs * 16 + l16;
      const size_t base = ((size_t)b * Cn + c) * Nn + n0 + ni * 32 + ns * 16 + quad * 4;
      const f32x4 xr1 = *(const f32x4*)(x3 + base);
      const f32x4 xr2 = *(const f32x4*)(xt + base);
      f32x4 o1, o2;
#pragma unroll
      for (int jj = 0; jj < 4; ++jj) {
        o1[jj] = g1 * acc[ns][cs][0][jj] * rv[jj] + xr1[jj];
        o2[jj] = g2 * acc[ns][cs][1][jj] * rv[jj] + xr2[jj];
      }
      *(f32x4*)(out1 + base) = o1;
      *(f32x4*)(out2 + base) = o2;
    }
  }
}

// ---------------------------------------------------------------------------
extern "C" void kernel_launch(void* const* d_in, const int* in_sizes, int n_in,
                              void* d_out, int out_size, void* d_ws, size_t ws_size,
                              hipStream_t stream) {
  const float* x1  = (const float*)d_in[0];
  const float* x2  = (const float*)d_in[1];
  const float* x3  = (const float*)d_in[2];
  const float* xt  = (const float*)d_in[3];
  const float* Wq  = (const float*)d_in[4];
  const float* bq  = (const float*)d_in[5];
  const float* Wk  = (const float*)d_in[6];
  const float* bk  = (const float*)d_in[7];
  const float* Wk2 = (const float*)d_in[8];
  const float* bk2 = (const float*)d_in[9];
  const float* Wv  = (const float*)d_in[10];
  const float* bv  = (const float*)d_in[11];
  const float* Wv2 = (const float*)d_in[12];
  const float* bv2 = (const float*)d_in[13];
  const float* gamma  = (const float*)d_in[14];
  const float* gamma2 = (const float*)d_in[15];

  float* outp = (float*)d_out;
  float* attn = outp;                                   // B*N*N
  float* out1 = outp + (size_t)Bn * Nn * Nn;            // B*C*N
  float* out2 = out1 + (size_t)Bn * Cn * Nn;

  _Float16* qt  = (_Float16*)d_ws;                      // B*N*CQ f16
  _Float16* k1t = qt + (size_t)Bn * Nn * CQn;
  _Float16* k2t = k1t + (size_t)Bn * Nn * CQn;
  _Float16* v   = k2t + (size_t)Bn * Nn * CQn;          // B*C*N f16
  _Float16* vt  = v + (size_t)Bn * Cn * Nn;

  proj_all<<<dim3(Nn / 64, Bn, 5), 256, 0, stream>>>(
      x1, x2, x3, xt, Wq, bq, Wk, bk, Wk2, bk2, Wv, bv, Wv2, bv2,
      qt, k1t, k2t, v, vt);
  attn_flash<<<dim3(Bn * Nn / 64), 1024, 0, stream>>>(
      qt, k1t, k2t, v, vt, x3, xt, gamma, gamma2, attn, out1, out2);
}